// Round 18
// baseline (278.360 us; speedup 1.0000x reference)
//
#include <hip/hip_runtime.h>
#include <stdint.h>

typedef __attribute__((ext_vector_type(8))) short s8v;     // 8 x bf16 bits
typedef __attribute__((ext_vector_type(4))) float f32x4;

#define HEADS 16
#define DH    64
#define SEG   512
#define PM    16
#define NKV   528      // PM + SEG
#define DIM   1024

// frag-major layouts (elements, per sh = seg*16+head):
//  Q: 512x64  -> off = ((rb*2+kk)*64 + lg*16 + lr)*8 + j
//  K: 576x64  -> off = ch*4096 + ((ni*2+kk)*64 + lg*16 + lr)*8 + j
//  V: 576x64  -> off = ch*4096 + ((kk*4+oi)*64 + lg*16 + lr)*8 + j

__device__ __forceinline__ unsigned short f2bf(float f) {
  union { float f; unsigned u; } v; v.f = f;
  unsigned r = v.u + 0x7fffu + ((v.u >> 16) & 1u);
  return (unsigned short)(r >> 16);
}

__device__ __forceinline__ void mfma_bf16(f32x4& c, s8v a, s8v b) {
  asm("v_mfma_f32_16x16x32_bf16 %0, %1, %2, %0" : "+v"(c) : "v"(a), "v"(b));
}

__device__ __forceinline__ void gload_lds16(const unsigned short* g, unsigned short* l) {
  __builtin_amdgcn_global_load_lds(
      (const __attribute__((address_space(1))) unsigned int*)g,
      (__attribute__((address_space(3))) unsigned int*)l, 16, 0, 0);
}

// ---------------- 256x256 K-loop: 8 waves (128x64 each), 2-buffer, 1 barrier/K-step ----------------
// Same R11/R17-proven sync skeleton; tile widened again to halve convoy events per
// unit work (R17 confirmed the event-cost model: 128->256 cols bought -10%).
// LDS: (A 16KB + B 16KB) x 2 bufs = 64KB -> 2 blocks/CU = 16 waves/CU.
// Staged row r lands at elem r*32 (A) / 8192+r*32 (B) continuously across both
// 128-row issues (4096+(r-128)*32 == r*32), so read offsets extend unchanged.
__device__ __forceinline__ void kloop_256sq(const unsigned short* A, const unsigned short* Bt,
                                            int m0, int n0, unsigned short* lds,
                                            f32x4 (&acc)[8][4]) {
  int tid = threadIdx.x, lane = tid & 63, wid = tid >> 6;
  int row = tid >> 2, sl = tid & 3;                  // 128 rows per 8KB issue
  int kg = (sl ^ ((row >> 1) & 3)) * 8;              // pre-swizzled global source (rule 21)
  const unsigned short* ga1 = A  + (size_t)(m0 + row) * DIM + kg;
  const unsigned short* ga2 = A  + (size_t)(m0 + row + 128) * DIM + kg;   // same kg: 128 ≡ 0 mod (2*4)
  const unsigned short* gb1 = Bt + (size_t)(n0 + row) * DIM + kg;
  const unsigned short* gb2 = Bt + (size_t)(n0 + row + 128) * DIM + kg;
  int wr = wid >> 2, wc = wid & 3;                   // 2M x 4N waves
  int mb = wr * 128, nb = wc * 64;
  int lr = lane & 15, lg = lane >> 4;

  int aoff[8], boff[4];
#pragma unroll
  for (int i = 0; i < 8; i++) {
    int ra = mb + i * 16 + lr;
    aoff[i] = ra * 32 + (lg ^ ((ra >> 1) & 3)) * 8;
  }
#pragma unroll
  for (int j = 0; j < 4; j++) {
    int rb = nb + j * 16 + lr;
    boff[j] = 8192 + rb * 32 + (lg ^ ((rb >> 1) & 3)) * 8;
  }

  auto stage = [&](int t) {
    unsigned short* d = lds + (t & 1) * 16384;       // 32KB buffers
    int kt = t * 32;
    gload_lds16(ga1 + kt, d + wid * 512);            // A rows 0-127
    gload_lds16(ga2 + kt, d + 4096 + wid * 512);     // A rows 128-255
    gload_lds16(gb1 + kt, d + 8192 + wid * 512);     // B cols 0-127
    gload_lds16(gb2 + kt, d + 12288 + wid * 512);    // B cols 128-255
  };

  stage(0);

  for (int t = 0; t < 32; ++t) {
    asm volatile("s_waitcnt vmcnt(0)" ::: "memory"); // stage(t): issued 1 full tile ago
    __builtin_amdgcn_s_barrier();
    asm volatile("" ::: "memory");
    if (t + 1 < 32) stage(t + 1);
    const unsigned short* bc = lds + (t & 1) * 16384;
    s8v a[8], b[4];
#pragma unroll
    for (int i = 0; i < 8; i++) a[i] = *(const s8v*)&bc[aoff[i]];
#pragma unroll
    for (int j = 0; j < 4; j++) b[j] = *(const s8v*)&bc[boff[j]];
    __builtin_amdgcn_s_setprio(1);
#pragma unroll
    for (int i = 0; i < 8; i++)
#pragma unroll
      for (int j = 0; j < 4; j++)
        mfma_bf16(acc[i][j], a[i], b[j]);
    __builtin_amdgcn_s_setprio(0);
  }
}

// ---------------- 128x256 K-loop (R17-proven, kept for gemm_out) ----------------
__device__ __forceinline__ void kloop_128x256(const unsigned short* A, const unsigned short* Bt,
                                              int m0, int n0, unsigned short* lds,
                                              f32x4 (&acc)[4][4]) {
  int tid = threadIdx.x, lane = tid & 63, wid = tid >> 6;
  int row = tid >> 2, sl = tid & 3;
  int kg = (sl ^ ((row >> 1) & 3)) * 8;
  const unsigned short* ga  = A  + (size_t)(m0 + row) * DIM + kg;
  const unsigned short* gb1 = Bt + (size_t)(n0 + row) * DIM + kg;
  const unsigned short* gb2 = Bt + (size_t)(n0 + row + 128) * DIM + kg;
  int mb = (wid >> 2) * 64, nb = (wid & 3) * 64;
  int lr = lane & 15, lg = lane >> 4;

  int aoff[4], boff[4];
#pragma unroll
  for (int i = 0; i < 4; i++) {
    int ra = mb + i * 16 + lr;
    aoff[i] = ra * 32 + (lg ^ ((ra >> 1) & 3)) * 8;
    int rb = nb + i * 16 + lr;
    boff[i] = 4096 + rb * 32 + (lg ^ ((rb >> 1) & 3)) * 8;
  }

  auto stage = [&](int t) {
    unsigned short* d = lds + (t & 1) * 12288;       // 24KB buffers
    int kt = t * 32;
    gload_lds16(ga + kt, d + wid * 512);
    gload_lds16(gb1 + kt, d + 4096 + wid * 512);
    gload_lds16(gb2 + kt, d + 8192 + wid * 512);
  };

  stage(0);

  for (int t = 0; t < 32; ++t) {
    asm volatile("s_waitcnt vmcnt(0)" ::: "memory");
    __builtin_amdgcn_s_barrier();
    asm volatile("" ::: "memory");
    if (t + 1 < 32) stage(t + 1);
    const unsigned short* bc = lds + (t & 1) * 12288;
    s8v a[4], b[4];
#pragma unroll
    for (int i = 0; i < 4; i++) a[i] = *(const s8v*)&bc[aoff[i]];
#pragma unroll
    for (int i = 0; i < 4; i++) b[i] = *(const s8v*)&bc[boff[i]];
    __builtin_amdgcn_s_setprio(1);
#pragma unroll
    for (int i = 0; i < 4; i++)
#pragma unroll
      for (int j = 0; j < 4; j++)
        mfma_bf16(acc[i][j], a[i], b[j]);
    __builtin_amdgcn_s_setprio(0);
  }
}

// ---------------- fused prep: rmsnorm + transposes + rope table + pm + vpad ----------------
#define NB_RMS   16384
#define NB_TWQKV 3072     // 96 x 32
#define NB_TWOUT 1024     // 32 x 32
#define NB_ROPE  1024
#define NB_PM    2048
#define NB_VPAD  6144

__global__ __launch_bounds__(256) void fused_prep(
    const float* seq, const float* norm_w, const float* w_qkv, const float* w_out,
    const float* pm_k, const float* pm_v,
    unsigned short* xn, unsigned short* wqkvT, unsigned short* woutT,
    float* costab, float* sintab, unsigned short* k_ws, unsigned short* v_ws) {
  __shared__ float smem[32 * 33];   // transpose tile; rmsnorm uses smem[0..3]
  int b = blockIdx.x, tid = threadIdx.x;

  if (b < NB_RMS) {
    float4 v = ((const float4*)(seq + (size_t)b * DIM))[tid];
    float ss = v.x * v.x + v.y * v.y + v.z * v.z + v.w * v.w;
    #pragma unroll
    for (int o = 32; o > 0; o >>= 1) ss += __shfl_xor(ss, o);
    if ((tid & 63) == 0) smem[tid >> 6] = ss;
    __syncthreads();
    ss = smem[0] + smem[1] + smem[2] + smem[3];
    float rs = rsqrtf(ss * (1.0f / 1024.0f) + 1e-6f);
    float4 wv = ((const float4*)norm_w)[tid];
    ushort4 o;
    o.x = f2bf(v.x * rs * wv.x); o.y = f2bf(v.y * rs * wv.y);
    o.z = f2bf(v.z * rs * wv.z); o.w = f2bf(v.w * rs * wv.w);
    ((ushort4*)(xn + (size_t)b * DIM))[tid] = o;
    return;
  }
  b -= NB_RMS;

  if (b < NB_TWQKV + NB_TWOUT) {
    const float* in; unsigned short* out; int N, bx, by;
    if (b < NB_TWQKV) { in = w_qkv; out = wqkvT; N = 3072; bx = b % 96; by = b / 96; }
    else { int b2 = b - NB_TWQKV; in = w_out; out = woutT; N = 1024; bx = b2 % 32; by = b2 / 32; }
    int K = 1024;
    int n0 = bx * 32, k0 = by * 32;
    int tx = tid & 31, ty = tid >> 5;   // (32,8)
    float (*tile)[33] = (float(*)[33])smem;
    for (int i = ty; i < 32; i += 8) tile[i][tx] = in[(size_t)(k0 + i) * N + n0 + tx];
    __syncthreads();
    for (int i = ty; i < 32; i += 8) out[(size_t)(n0 + i) * K + k0 + tx] = f2bf(tile[tx][i]);
    return;
  }
  b -= NB_TWQKV + NB_TWOUT;

  if (b < NB_ROPE) {
    int idx = b * 256 + tid;   // 8192*32
    int n = idx >> 5, p = idx & 31;
    float inv = expf(-(float)p * (9.210340371976184f / 32.0f));   // 10000^(-p/32)
    float ang = (float)n * inv;
    costab[idx] = cosf(ang);
    sintab[idx] = sinf(ang);
    return;
  }
  b -= NB_ROPE;

  if (b < NB_PM) {
    int idx = b * 256 + tid;   // 32*16*16*64
    int d = idx & 63, t = (idx >> 6) & 15, h = (idx >> 10) & 15, bw = idx >> 14;
    int sh = bw * 16 + h;
    float kv = pm_k[((h * 16 + t) << 6) + d];
    float vv = pm_v[((h * 16 + t) << 6) + d];
    k_ws[(size_t)sh * 36864 + (((d >> 5) * 64) + ((d >> 3) & 3) * 16 + t) * 8 + (d & 7)] = f2bf(kv);
    v_ws[(size_t)sh * 36864 + (((d >> 4) * 64) + (t >> 3) * 16 + (d & 15)) * 8 + (t & 7)] = f2bf(vv);
    return;
  }
  b -= NB_PM;

  {
    int idx = b * 256 + tid;   // 512*64*48
    int t = idx % 48; int rest = idx / 48; int d = rest & 63; int sh = rest >> 6;
    int key = NKV + t;                           // 528..575, ch=8
    int kk = (key >> 5) & 1, lg = (key >> 3) & 3, j = key & 7;
    v_ws[(size_t)sh * 36864 + 8 * 4096 + ((kk * 4 + (d >> 4)) * 64 + lg * 16 + (d & 15)) * 8 + j] = 0;
  }
}

// ---------------- GEMM 1: qkv = xn @ WqkvT, 256x256 tile, fused rope + scatter ----------------
// Grid: x = m-tile (fast, 64), y = n-tile (12 of 256 cols); 256-col blocks align with
// q/k/v boundaries -> type stays wave-uniform.
__global__ __launch_bounds__(512) void gemm_qkv(const unsigned short* A, const unsigned short* Bt,
                                                const float* costab, const float* sintab,
                                                unsigned short* q_ws, unsigned short* k_ws,
                                                unsigned short* v_ws) {
  __shared__ unsigned short lds[32768];   // 2 x 32KB K-tile buffers (2 blocks/CU)
  int m0 = blockIdx.x * 256, n0 = blockIdx.y * 256;
  f32x4 acc[8][4] = {};
  kloop_256sq(A, Bt, m0, n0, lds, acc);

  int tid = threadIdx.x, lane = tid & 63, wid = tid >> 6;
  int lr = lane & 15, lg = lane >> 4;
  int mb = (wid >> 2) * 128, nb = (wid & 3) * 64;

  // epilogue: rope on q/k, scatter into frag-major layouts
  #pragma unroll
  for (int i = 0; i < 8; i++) {
    #pragma unroll
    for (int j = 0; j < 4; j++) {
      int colbase = n0 + nb + j * 16;          // wave-uniform
      int type = colbase >> 10;                // 0=q 1=k 2=v
      int hh = (colbase & 1023) >> 6;
      int d0 = colbase & 63;
      int d = d0 + lr;
      int rowt = m0 + mb + i * 16;
      int rowb = rowt + lg * 4;
      f32x4 v = acc[i][j];
      if (type < 2) {
        int p = d >> 1;
        float vr[4];
        #pragma unroll
        for (int r = 0; r < 4; r++) {
          float partner = __shfl_xor(v[r], 1);
          int npos = (rowb + r) & 8191;
          float cth = costab[npos * 32 + p];
          float sth = sintab[npos * 32 + p];
          vr[r] = (d & 1) ? (v[r] * cth + partner * sth)
                          : (v[r] * cth - partner * sth);
        }
        int kk2 = d >> 5, lg2 = (d >> 3) & 3, j2 = d & 7;
        #pragma unroll
        for (int r = 0; r < 4; r++) {
          int m = rowb + r;
          int bw = m >> 9, pos = m & 511;
          int sh2 = bw * 16 + hh;
          unsigned short bits = f2bf(vr[r]);
          if (type == 0)
            q_ws[(size_t)sh2 * 32768 + ((((pos >> 4) * 2 + kk2) * 64) + lg2 * 16 + (pos & 15)) * 8 + j2] = bits;
          else {
            int key = PM + pos;
            k_ws[(size_t)sh2 * 36864 + (key >> 6) * 4096 +
                 (((((key >> 4) & 3) * 2 + kk2) * 64) + lg2 * 16 + (key & 15)) * 8 + j2] = bits;
          }
        }
      } else {
        // V: thread holds (key0..key0+3, d=d0+lr); pack 4 keys -> one 8B store
        int bw = rowb >> 9, sh2 = bw * 16 + hh;
        int key0 = PM + (rowb & 511);
        int chn = key0 >> 6, kk2 = (key0 >> 5) & 1, lg2 = (key0 >> 3) & 3, j0 = key0 & 7;
        int oi2 = d0 >> 4;
        ushort4 pk;
        pk.x = f2bf(v[0]); pk.y = f2bf(v[1]); pk.z = f2bf(v[2]); pk.w = f2bf(v[3]);
        *(ushort4*)&v_ws[(size_t)sh2 * 36864 + chn * 4096 +
                         ((kk2 * 4 + oi2) * 64 + lg2 * 16 + lr) * 8 + j0] = pk;
      }
    }
  }
}

// ---------------- attention (R14: deferred row-sum reduce + K reg-dbuf + barrier) ----------------
__global__ __launch_bounds__(256) void attn_k(const unsigned short* q_ws,
                                              const unsigned short* k_ws,
                                              const unsigned short* v_ws,
                                              unsigned short* attn_out) {
  __shared__ unsigned short Pls[128 * 72];  // per-wave 32 rows
  int bid = blockIdx.x;
  int qt = bid & 3, h = (bid >> 2) & 15, s = bid >> 6;
  int sh = s * 16 + h;
  int tid = threadIdx.x, lane = tid & 63, wid = tid >> 6;
  int lr = lane & 15, lg = lane >> 4;
  int qrow0 = qt * 128 + wid * 32;

  const unsigned short* qsh = q_ws + (size_t)sh * 32768;
  const unsigned short* kbase = k_ws + (size_t)sh * 36864;
  const unsigned short* vbase = v_ws + (size_t)sh * 36864;

  s8v qf[2][2];
  #pragma unroll
  for (int mi = 0; mi < 2; mi++) {
    int rb = qt * 8 + wid * 2 + mi;
    #pragma unroll
    for (int kk = 0; kk < 2; kk++)
      qf[mi][kk] = *(const s8v*)&qsh[(((rb * 2 + kk) * 64) + lane) * 8];
  }

  f32x4 O[2][4] = {};
  float lrun[2][4] = {};          // per-lane PARTIAL row sums (reduced after loop)
  int nchunk = 2 * qt + 3;

  // preload chunk 0's K fragments
  s8v kf[4][2];
  #pragma unroll
  for (int ni = 0; ni < 4; ni++)
    #pragma unroll
    for (int kk = 0; kk < 2; kk++)
      kf[ni][kk] = *(const s8v*)&kbase[((ni * 2 + kk) * 64 + lane) * 8];

  for (int cc = 0; cc < nchunk; ++cc) {
    const unsigned short* vch = vbase + cc * 4096;
    int kc0 = cc * 64;

    f32x4 S[2][4] = {};
    __builtin_amdgcn_s_setprio(1);
    #pragma unroll
    for (int kk = 0; kk < 2; kk++)
      #pragma unroll
      for (int ni = 0; ni < 4; ni++)
        #pragma unroll
        for (int mi = 0; mi < 2; mi++)
          mfma_bf16(S[mi][ni], qf[mi][kk], kf[ni][kk]);
    __builtin_amdgcn_s_setprio(0);

    // V frags for this chunk (consumed after softmax)
    s8v vf[4][2];
    #pragma unroll
    for (int oi = 0; oi < 4; oi++)
      #pragma unroll
      for (int kk = 0; kk < 2; kk++)
        vf[oi][kk] = *(const s8v*)&vch[((kk * 4 + oi) * 64 + lane) * 8];

    // prefetch next chunk's K frags (latency hides under softmax+PV)
    int ccn = (cc + 1 < nchunk) ? cc + 1 : cc;
    const unsigned short* kchn = kbase + ccn * 4096;
    s8v kf_n[4][2];
    #pragma unroll
    for (int ni = 0; ni < 4; ni++)
      #pragma unroll
      for (int kk = 0; kk < 2; kk++)
        kf_n[ni][kk] = *(const s8v*)&kchn[((ni * 2 + kk) * 64 + lane) * 8];

    #pragma unroll
    for (int mi = 0; mi < 2; mi++) {
      bool needmask = (kc0 + 47) > (qrow0 + mi * 16);   // wave-uniform
      if (needmask) {
        #pragma unroll
        for (int r = 0; r < 4; r++) {
          int qpos = qrow0 + mi * 16 + lg * 4 + r;
          float rs = 0.0f;
          #pragma unroll
          for (int ni = 0; ni < 4; ni++) {
            int col = kc0 + ni * 16 + lr;
            bool ok = (col < PM) || ((col - PM) <= qpos);
            float p = ok ? __expf(S[mi][ni][r] * 0.125f) : 0.0f;
            S[mi][ni][r] = p;
            rs += p;
          }
          lrun[mi][r] += rs;      // per-lane partial; cross-lane reduce deferred
        }
      } else {
        #pragma unroll
        for (int r = 0; r < 4; r++) {
          float rs = 0.0f;
          #pragma unroll
          for (int ni = 0; ni < 4; ni++) {
            float p = __expf(S[mi][ni][r] * 0.125f);
            S[mi][ni][r] = p;
            rs += p;
          }
          lrun[mi][r] += rs;      // per-lane partial; cross-lane reduce deferred
        }
      }
    }

    // P -> LDS (wave-private region; scalar ushort writes, s8v reads — proven pattern)
    #pragma unroll
    for (int mi = 0; mi < 2; mi++)
      #pragma unroll
      for (int ni = 0; ni < 4; ni++)
        #pragma unroll
        for (int r = 0; r < 4; r++)
          Pls[(wid * 32 + mi * 16 + lg * 4 + r) * 72 + ni * 16 + lr] = f2bf(S[mi][ni][r]);

    __builtin_amdgcn_s_setprio(1);
    #pragma unroll
    for (int kk = 0; kk < 2; kk++) {
      s8v pa[2];
      #pragma unroll
      for (int mi = 0; mi < 2; mi++)
        pa[mi] = *(const s8v*)&Pls[(wid * 32 + mi * 16 + lr) * 72 + kk * 32 + lg * 8];
      #pragma unroll
      for (int oi = 0; oi < 4; oi++)
        #pragma unroll
        for (int mi = 0; mi < 2; mi++)
          mfma_bf16(O[mi][oi], pa[mi], vf[oi][kk]);
    }
    __builtin_amdgcn_s_setprio(0);

    // rotate prefetched K into place
    #pragma unroll
    for (int ni = 0; ni < 4; ni++)
      #pragma unroll
      for (int kk = 0; kk < 2; kk++)
        kf[ni][kk] = kf_n[ni][kk];

    __syncthreads();   // keeps waves' chunk loads aligned (R12: removal cost 8us)
  }

  // deferred cross-lane reduce: keys were spread over lr within each lg group
  #pragma unroll
  for (int mi = 0; mi < 2; mi++)
    #pragma unroll
    for (int r = 0; r < 4; r++) {
      float v = lrun[mi][r];
      #pragma unroll
      for (int o = 1; o < 16; o <<= 1) v += __shfl_xor(v, o);
      lrun[mi][r] = v;
    }

  int mbase = (s >> 4) * 8192 + (s & 15) * 512;
  #pragma unroll
  for (int mi = 0; mi < 2; mi++)
    #pragma unroll
    for (int r = 0; r < 4; r++) {
      float inv = 1.0f / lrun[mi][r];
      int qpos = qrow0 + mi * 16 + lg * 4 + r;
      size_t m = (size_t)mbase + qpos;
      #pragma unroll
      for (int oi = 0; oi < 4; oi++)
        attn_out[m * DIM + h * 64 + oi * 16 + lr] = f2bf(O[mi][oi][r] * inv);
    }
}

// ---------------- GEMM 2: out = attn @ WoutT + b (R17-proven 128x256 path) ----------------
__global__ __launch_bounds__(512) void gemm_out(const unsigned short* A, const unsigned short* Bt,
                                                const float* bias, float* out) {
  __shared__ unsigned short lds[24576];   // 2 x 24KB K-tile buffers
  int m0 = blockIdx.x * 128, n0 = blockIdx.y * 256;
  f32x4 acc[4][4] = {};
  kloop_128x256(A, Bt, m0, n0, lds, acc);

  int tid = threadIdx.x, lane = tid & 63, wid = tid >> 6;
  int lr = lane & 15, lg = lane >> 4;
  int mb = (wid >> 2) * 64, nb = (wid & 3) * 64;

  #pragma unroll
  for (int i = 0; i < 4; i++)
    #pragma unroll
    for (int j = 0; j < 4; j++) {
      int c = n0 + nb + j * 16 + lr;
      float bv = bias[c];
      #pragma unroll
      for (int r = 0; r < 4; r++) {
        int m = m0 + mb + i * 16 + lg * 4 + r;
        out[(size_t)m * DIM + c] = acc[i][j][r] + bv;
      }
    }
}

// ---------------- launch ----------------
extern "C" void kernel_launch(void* const* d_in, const int* in_sizes, int n_in,
                              void* d_out, int out_size, void* d_ws, size_t ws_size,
                              hipStream_t stream) {
  (void)in_sizes; (void)n_in; (void)out_size; (void)ws_size;
  const float* seq    = (const float*)d_in[0];
  const float* norm_w = (const float*)d_in[1];
  const float* w_qkv  = (const float*)d_in[2];
  const float* pm_k   = (const float*)d_in[3];
  const float* pm_v   = (const float*)d_in[4];
  const float* w_out  = (const float*)d_in[5];
  const float* b_out  = (const float*)d_in[6];
  float* out = (float*)d_out;

  char* ws = (char*)d_ws;
  unsigned short* xn    = (unsigned short*)(ws);              // 33,554,432 B
  unsigned short* wqkvT = (unsigned short*)(ws + 33554432);   //  6,291,456
  unsigned short* woutT = (unsigned short*)(ws + 39845888);   //  2,097,152
  float* costab         = (float*)(ws + 41943040);            //  1,048,576
  float* sintab         = (float*)(ws + 42991616);            //  1,048,576
  unsigned short* q_ws  = (unsigned short*)(ws + 44040192);   // 33,554,432
  unsigned short* k_ws  = (unsigned short*)(ws + 77594624);   // 37,748,736
  unsigned short* v_ws  = (unsigned short*)(ws + 115343360);  // 37,748,736
  unsigned short* attno = (unsigned short*)(ws + 153092096);  // 33,554,432 (end 186,646,528)

  int nb_prep = NB_RMS + NB_TWQKV + NB_TWOUT + NB_ROPE + NB_PM + NB_VPAD;  // 29696
  fused_prep<<<nb_prep, 256, 0, stream>>>(seq, norm_w, w_qkv, w_out, pm_k, pm_v,
                                          xn, wqkvT, woutT, costab, sintab, k_ws, v_ws);
  gemm_qkv<<<dim3(64, 12), 512, 0, stream>>>(xn, wqkvT, costab, sintab, q_ws, k_ws, v_ws);
  attn_k<<<2048, 256, 0, stream>>>(q_ws, k_ws, v_ws, attno);
  gemm_out<<<dim3(128, 4), 512, 0, stream>>>(attno, woutT, b_out, out);
}

// Round 19
// 267.591 us; speedup vs baseline: 1.0402x; 1.0402x over previous
//
#include <hip/hip_runtime.h>
#include <stdint.h>

typedef __attribute__((ext_vector_type(8))) short s8v;     // 8 x bf16 bits
typedef __attribute__((ext_vector_type(4))) float f32x4;

#define HEADS 16
#define DH    64
#define SEG   512
#define PM    16
#define NKV   528      // PM + SEG
#define DIM   1024

// frag-major layouts (elements, per sh = seg*16+head):
//  Q: 512x64  -> off = ((rb*2+kk)*64 + lg*16 + lr)*8 + j
//  K: 576x64  -> off = ch*4096 + ((ni*2+kk)*64 + lg*16 + lr)*8 + j
//  V: 576x64  -> off = ch*4096 + ((kk*4+oi)*64 + lg*16 + lr)*8 + j

__device__ __forceinline__ unsigned short f2bf(float f) {
  union { float f; unsigned u; } v; v.f = f;
  unsigned r = v.u + 0x7fffu + ((v.u >> 16) & 1u);
  return (unsigned short)(r >> 16);
}

__device__ __forceinline__ void mfma_bf16(f32x4& c, s8v a, s8v b) {
  asm("v_mfma_f32_16x16x32_bf16 %0, %1, %2, %0" : "+v"(c) : "v"(a), "v"(b));
}

__device__ __forceinline__ void gload_lds16(const unsigned short* g, unsigned short* l) {
  __builtin_amdgcn_global_load_lds(
      (const __attribute__((address_space(1))) unsigned int*)g,
      (__attribute__((address_space(3))) unsigned int*)l, 16, 0, 0);
}

// ---------------- 128x256 K-loop: 8 waves, 2-buffer, 1 barrier/K-step ----------------
// R17-proven optimum of the tile family: 128x256 @ 3 blocks/CU (24 waves/CU).
// R18 showed 256x256 regresses (occupancy-bounded: event-halving loses to resync
// cost once blocks/CU < 3). Sync skeleton: vmcnt(0) + barrier + stage-after-barrier.
__device__ __forceinline__ void kloop_128x256(const unsigned short* A, const unsigned short* Bt,
                                              int m0, int n0, unsigned short* lds,
                                              f32x4 (&acc)[4][4]) {
  int tid = threadIdx.x, lane = tid & 63, wid = tid >> 6;
  int row = tid >> 2, sl = tid & 3;                  // row 0..127 (512 threads)
  int kg = (sl ^ ((row >> 1) & 3)) * 8;              // pre-swizzled global source (rule 21)
  const unsigned short* ga  = A  + (size_t)(m0 + row) * DIM + kg;
  const unsigned short* gb1 = Bt + (size_t)(n0 + row) * DIM + kg;
  const unsigned short* gb2 = Bt + (size_t)(n0 + row + 128) * DIM + kg;
  int mb = (wid >> 2) * 64, nb = (wid & 3) * 64;
  int lr = lane & 15, lg = lane >> 4;

  // read offsets (swizzled): elem = row*32 + (lg ^ ((row>>1)&3))*8 ; B at +4096
  int aoff[4], boff[4];
#pragma unroll
  for (int i = 0; i < 4; i++) {
    int ra = mb + i * 16 + lr;
    aoff[i] = ra * 32 + (lg ^ ((ra >> 1) & 3)) * 8;
    int rb = nb + i * 16 + lr;
    boff[i] = 4096 + rb * 32 + (lg ^ ((rb >> 1) & 3)) * 8;
  }

  auto stage = [&](int t) {
    unsigned short* d = lds + (t & 1) * 12288;       // 24KB buffers
    int kt = t * 32;
    gload_lds16(ga + kt, d + wid * 512);             // A 128x32 (8KB, one issue)
    gload_lds16(gb1 + kt, d + 4096 + wid * 512);     // B cols 0-127
    gload_lds16(gb2 + kt, d + 8192 + wid * 512);     // B cols 128-255
  };

  stage(0);

  for (int t = 0; t < 32; ++t) {
    asm volatile("s_waitcnt vmcnt(0)" ::: "memory"); // stage(t): issued 1 full tile ago
    __builtin_amdgcn_s_barrier();
    asm volatile("" ::: "memory");
    if (t + 1 < 32) stage(t + 1);
    const unsigned short* bc = lds + (t & 1) * 12288;
    s8v a[4], b[4];
#pragma unroll
    for (int i = 0; i < 4; i++) a[i] = *(const s8v*)&bc[aoff[i]];
#pragma unroll
    for (int i = 0; i < 4; i++) b[i] = *(const s8v*)&bc[boff[i]];
    __builtin_amdgcn_s_setprio(1);
#pragma unroll
    for (int i = 0; i < 4; i++)
#pragma unroll
      for (int j = 0; j < 4; j++)
        mfma_bf16(acc[i][j], a[i], b[j]);
    __builtin_amdgcn_s_setprio(0);
  }
}

// ---------------- fused prep: rmsnorm + transposes + rope table + pm + vpad ----------------
#define NB_RMS   16384
#define NB_TWQKV 3072     // 96 x 32
#define NB_TWOUT 1024     // 32 x 32
#define NB_ROPE  1024
#define NB_PM    2048
#define NB_VPAD  6144

__global__ __launch_bounds__(256) void fused_prep(
    const float* seq, const float* norm_w, const float* w_qkv, const float* w_out,
    const float* pm_k, const float* pm_v,
    unsigned short* xn, unsigned short* wqkvT, unsigned short* woutT,
    float* costab, float* sintab, unsigned short* k_ws, unsigned short* v_ws) {
  __shared__ float smem[32 * 33];   // transpose tile; rmsnorm uses smem[0..3]
  int b = blockIdx.x, tid = threadIdx.x;

  if (b < NB_RMS) {
    // ---- rmsnorm row b ----
    float4 v = ((const float4*)(seq + (size_t)b * DIM))[tid];
    float ss = v.x * v.x + v.y * v.y + v.z * v.z + v.w * v.w;
    #pragma unroll
    for (int o = 32; o > 0; o >>= 1) ss += __shfl_xor(ss, o);
    if ((tid & 63) == 0) smem[tid >> 6] = ss;
    __syncthreads();
    ss = smem[0] + smem[1] + smem[2] + smem[3];
    float rs = rsqrtf(ss * (1.0f / 1024.0f) + 1e-6f);
    float4 wv = ((const float4*)norm_w)[tid];
    ushort4 o;
    o.x = f2bf(v.x * rs * wv.x); o.y = f2bf(v.y * rs * wv.y);
    o.z = f2bf(v.z * rs * wv.z); o.w = f2bf(v.w * rs * wv.w);
    ((ushort4*)(xn + (size_t)b * DIM))[tid] = o;
    return;
  }
  b -= NB_RMS;

  if (b < NB_TWQKV + NB_TWOUT) {
    // ---- transpose_w: [K][N] f32 -> [N][K] bf16 ----
    const float* in; unsigned short* out; int N, bx, by;
    if (b < NB_TWQKV) { in = w_qkv; out = wqkvT; N = 3072; bx = b % 96; by = b / 96; }
    else { int b2 = b - NB_TWQKV; in = w_out; out = woutT; N = 1024; bx = b2 % 32; by = b2 / 32; }
    int K = 1024;
    int n0 = bx * 32, k0 = by * 32;
    int tx = tid & 31, ty = tid >> 5;   // (32,8)
    float (*tile)[33] = (float(*)[33])smem;
    for (int i = ty; i < 32; i += 8) tile[i][tx] = in[(size_t)(k0 + i) * N + n0 + tx];
    __syncthreads();
    for (int i = ty; i < 32; i += 8) out[(size_t)(n0 + i) * K + k0 + tx] = f2bf(tile[tx][i]);
    return;
  }
  b -= NB_TWQKV + NB_TWOUT;

  if (b < NB_ROPE) {
    int idx = b * 256 + tid;   // 8192*32
    int n = idx >> 5, p = idx & 31;
    float inv = expf(-(float)p * (9.210340371976184f / 32.0f));   // 10000^(-p/32)
    float ang = (float)n * inv;
    costab[idx] = cosf(ang);
    sintab[idx] = sinf(ang);
    return;
  }
  b -= NB_ROPE;

  if (b < NB_PM) {
    int idx = b * 256 + tid;   // 32*16*16*64
    int d = idx & 63, t = (idx >> 6) & 15, h = (idx >> 10) & 15, bw = idx >> 14;
    int sh = bw * 16 + h;
    float kv = pm_k[((h * 16 + t) << 6) + d];
    float vv = pm_v[((h * 16 + t) << 6) + d];
    k_ws[(size_t)sh * 36864 + (((d >> 5) * 64) + ((d >> 3) & 3) * 16 + t) * 8 + (d & 7)] = f2bf(kv);
    v_ws[(size_t)sh * 36864 + (((d >> 4) * 64) + (t >> 3) * 16 + (d & 15)) * 8 + (t & 7)] = f2bf(vv);
    return;
  }
  b -= NB_PM;

  {
    int idx = b * 256 + tid;   // 512*64*48
    int t = idx % 48; int rest = idx / 48; int d = rest & 63; int sh = rest >> 6;
    int key = NKV + t;                           // 528..575, ch=8
    int kk = (key >> 5) & 1, lg = (key >> 3) & 3, j = key & 7;
    v_ws[(size_t)sh * 36864 + 8 * 4096 + ((kk * 4 + (d >> 4)) * 64 + lg * 16 + (d & 15)) * 8 + j] = 0;
  }
}

// ---------------- GEMM 1: qkv = xn @ WqkvT, fused rope + frag-major scatter ----------------
// Grid: x = m-tile (fast, 128), y = n-tile (12 of 256 cols). 256-col blocks align
// with q/k/v boundaries (multiples of 1024) -> type stays wave-uniform.
__global__ __launch_bounds__(512) void gemm_qkv(const unsigned short* A, const unsigned short* Bt,
                                                const float* costab, const float* sintab,
                                                unsigned short* q_ws, unsigned short* k_ws,
                                                unsigned short* v_ws) {
  __shared__ unsigned short lds[24576];   // 2 x 24KB K-tile buffers (3 blocks/CU)
  int m0 = blockIdx.x * 128, n0 = blockIdx.y * 256;
  f32x4 acc[4][4] = {};
  kloop_128x256(A, Bt, m0, n0, lds, acc);

  int tid = threadIdx.x, lane = tid & 63, wid = tid >> 6;
  int lr = lane & 15, lg = lane >> 4;
  int mb = (wid >> 2) * 64, nb = (wid & 3) * 64;

  // epilogue: rope on q/k, scatter into frag-major layouts
  #pragma unroll
  for (int i = 0; i < 4; i++) {
    #pragma unroll
    for (int j = 0; j < 4; j++) {
      int colbase = n0 + nb + j * 16;          // wave-uniform
      int type = colbase >> 10;                // 0=q 1=k 2=v
      int hh = (colbase & 1023) >> 6;
      int d0 = colbase & 63;
      int d = d0 + lr;
      int rowt = m0 + mb + i * 16;
      int rowb = rowt + lg * 4;
      f32x4 v = acc[i][j];
      if (type < 2) {
        int p = d >> 1;
        float vr[4];
        #pragma unroll
        for (int r = 0; r < 4; r++) {
          float partner = __shfl_xor(v[r], 1);
          int npos = (rowb + r) & 8191;
          float cth = costab[npos * 32 + p];
          float sth = sintab[npos * 32 + p];
          vr[r] = (d & 1) ? (v[r] * cth + partner * sth)
                          : (v[r] * cth - partner * sth);
        }
        int kk2 = d >> 5, lg2 = (d >> 3) & 3, j2 = d & 7;
        #pragma unroll
        for (int r = 0; r < 4; r++) {
          int m = rowb + r;
          int bw = m >> 9, pos = m & 511;
          int sh2 = bw * 16 + hh;
          unsigned short bits = f2bf(vr[r]);
          if (type == 0)
            q_ws[(size_t)sh2 * 32768 + ((((pos >> 4) * 2 + kk2) * 64) + lg2 * 16 + (pos & 15)) * 8 + j2] = bits;
          else {
            int key = PM + pos;
            k_ws[(size_t)sh2 * 36864 + (key >> 6) * 4096 +
                 (((((key >> 4) & 3) * 2 + kk2) * 64) + lg2 * 16 + (key & 15)) * 8 + j2] = bits;
          }
        }
      } else {
        // V: thread holds (key0..key0+3, d=d0+lr); pack 4 keys -> one 8B store
        int bw = rowb >> 9, sh2 = bw * 16 + hh;
        int key0 = PM + (rowb & 511);
        int chn = key0 >> 6, kk2 = (key0 >> 5) & 1, lg2 = (key0 >> 3) & 3, j0 = key0 & 7;
        int oi2 = d0 >> 4;
        ushort4 pk;
        pk.x = f2bf(v[0]); pk.y = f2bf(v[1]); pk.z = f2bf(v[2]); pk.w = f2bf(v[3]);
        *(ushort4*)&v_ws[(size_t)sh2 * 36864 + chn * 4096 +
                         ((kk2 * 4 + oi2) * 64 + lg2 * 16 + lr) * 8 + j0] = pk;
      }
    }
  }
}

// ---------------- attention (R14: deferred row-sum reduce + K reg-dbuf + barrier) ----------------
__global__ __launch_bounds__(256) void attn_k(const unsigned short* q_ws,
                                              const unsigned short* k_ws,
                                              const unsigned short* v_ws,
                                              unsigned short* attn_out) {
  __shared__ unsigned short Pls[128 * 72];  // per-wave 32 rows
  int bid = blockIdx.x;
  int qt = bid & 3, h = (bid >> 2) & 15, s = bid >> 6;
  int sh = s * 16 + h;
  int tid = threadIdx.x, lane = tid & 63, wid = tid >> 6;
  int lr = lane & 15, lg = lane >> 4;
  int qrow0 = qt * 128 + wid * 32;

  const unsigned short* qsh = q_ws + (size_t)sh * 32768;
  const unsigned short* kbase = k_ws + (size_t)sh * 36864;
  const unsigned short* vbase = v_ws + (size_t)sh * 36864;

  s8v qf[2][2];
  #pragma unroll
  for (int mi = 0; mi < 2; mi++) {
    int rb = qt * 8 + wid * 2 + mi;
    #pragma unroll
    for (int kk = 0; kk < 2; kk++)
      qf[mi][kk] = *(const s8v*)&qsh[(((rb * 2 + kk) * 64) + lane) * 8];
  }

  f32x4 O[2][4] = {};
  float lrun[2][4] = {};          // per-lane PARTIAL row sums (reduced after loop)
  int nchunk = 2 * qt + 3;

  // preload chunk 0's K fragments
  s8v kf[4][2];
  #pragma unroll
  for (int ni = 0; ni < 4; ni++)
    #pragma unroll
    for (int kk = 0; kk < 2; kk++)
      kf[ni][kk] = *(const s8v*)&kbase[((ni * 2 + kk) * 64 + lane) * 8];

  for (int cc = 0; cc < nchunk; ++cc) {
    const unsigned short* vch = vbase + cc * 4096;
    int kc0 = cc * 64;

    f32x4 S[2][4] = {};
    __builtin_amdgcn_s_setprio(1);
    #pragma unroll
    for (int kk = 0; kk < 2; kk++)
      #pragma unroll
      for (int ni = 0; ni < 4; ni++)
        #pragma unroll
        for (int mi = 0; mi < 2; mi++)
          mfma_bf16(S[mi][ni], qf[mi][kk], kf[ni][kk]);
    __builtin_amdgcn_s_setprio(0);

    // V frags for this chunk (consumed after softmax)
    s8v vf[4][2];
    #pragma unroll
    for (int oi = 0; oi < 4; oi++)
      #pragma unroll
      for (int kk = 0; kk < 2; kk++)
        vf[oi][kk] = *(const s8v*)&vch[((kk * 4 + oi) * 64 + lane) * 8];

    // prefetch next chunk's K frags (latency hides under softmax+PV)
    int ccn = (cc + 1 < nchunk) ? cc + 1 : cc;
    const unsigned short* kchn = kbase + ccn * 4096;
    s8v kf_n[4][2];
    #pragma unroll
    for (int ni = 0; ni < 4; ni++)
      #pragma unroll
      for (int kk = 0; kk < 2; kk++)
        kf_n[ni][kk] = *(const s8v*)&kchn[((ni * 2 + kk) * 64 + lane) * 8];

    #pragma unroll
    for (int mi = 0; mi < 2; mi++) {
      bool needmask = (kc0 + 47) > (qrow0 + mi * 16);   // wave-uniform
      if (needmask) {
        #pragma unroll
        for (int r = 0; r < 4; r++) {
          int qpos = qrow0 + mi * 16 + lg * 4 + r;
          float rs = 0.0f;
          #pragma unroll
          for (int ni = 0; ni < 4; ni++) {
            int col = kc0 + ni * 16 + lr;
            bool ok = (col < PM) || ((col - PM) <= qpos);
            float p = ok ? __expf(S[mi][ni][r] * 0.125f) : 0.0f;
            S[mi][ni][r] = p;
            rs += p;
          }
          lrun[mi][r] += rs;      // per-lane partial; cross-lane reduce deferred
        }
      } else {
        #pragma unroll
        for (int r = 0; r < 4; r++) {
          float rs = 0.0f;
          #pragma unroll
          for (int ni = 0; ni < 4; ni++) {
            float p = __expf(S[mi][ni][r] * 0.125f);
            S[mi][ni][r] = p;
            rs += p;
          }
          lrun[mi][r] += rs;      // per-lane partial; cross-lane reduce deferred
        }
      }
    }

    // P -> LDS (wave-private region; scalar ushort writes, s8v reads — proven pattern)
    #pragma unroll
    for (int mi = 0; mi < 2; mi++)
      #pragma unroll
      for (int ni = 0; ni < 4; ni++)
        #pragma unroll
        for (int r = 0; r < 4; r++)
          Pls[(wid * 32 + mi * 16 + lg * 4 + r) * 72 + ni * 16 + lr] = f2bf(S[mi][ni][r]);

    __builtin_amdgcn_s_setprio(1);
    #pragma unroll
    for (int kk = 0; kk < 2; kk++) {
      s8v pa[2];
      #pragma unroll
      for (int mi = 0; mi < 2; mi++)
        pa[mi] = *(const s8v*)&Pls[(wid * 32 + mi * 16 + lr) * 72 + kk * 32 + lg * 8];
      #pragma unroll
      for (int oi = 0; oi < 4; oi++)
        #pragma unroll
        for (int mi = 0; mi < 2; mi++)
          mfma_bf16(O[mi][oi], pa[mi], vf[oi][kk]);
    }
    __builtin_amdgcn_s_setprio(0);

    // rotate prefetched K into place
    #pragma unroll
    for (int ni = 0; ni < 4; ni++)
      #pragma unroll
      for (int kk = 0; kk < 2; kk++)
        kf[ni][kk] = kf_n[ni][kk];

    __syncthreads();   // keeps waves' chunk loads aligned (R12: removal cost 8us)
  }

  // deferred cross-lane reduce: keys were spread over lr within each lg group
  #pragma unroll
  for (int mi = 0; mi < 2; mi++)
    #pragma unroll
    for (int r = 0; r < 4; r++) {
      float v = lrun[mi][r];
      #pragma unroll
      for (int o = 1; o < 16; o <<= 1) v += __shfl_xor(v, o);
      lrun[mi][r] = v;
    }

  int mbase = (s >> 4) * 8192 + (s & 15) * 512;
  #pragma unroll
  for (int mi = 0; mi < 2; mi++)
    #pragma unroll
    for (int r = 0; r < 4; r++) {
      float inv = 1.0f / lrun[mi][r];
      int qpos = qrow0 + mi * 16 + lg * 4 + r;
      size_t m = (size_t)mbase + qpos;
      #pragma unroll
      for (int oi = 0; oi < 4; oi++)
        attn_out[m * DIM + h * 64 + oi * 16 + lr] = f2bf(O[mi][oi][r] * inv);
    }
}

// ---------------- GEMM 2: out = attn @ WoutT + b (R17-proven 128x256 path) ----------------
__global__ __launch_bounds__(512) void gemm_out(const unsigned short* A, const unsigned short* Bt,
                                                const float* bias, float* out) {
  __shared__ unsigned short lds[24576];   // 2 x 24KB K-tile buffers
  int m0 = blockIdx.x * 128, n0 = blockIdx.y * 256;
  f32x4 acc[4][4] = {};
  kloop_128x256(A, Bt, m0, n0, lds, acc);

  int tid = threadIdx.x, lane = tid & 63, wid = tid >> 6;
  int lr = lane & 15, lg = lane >> 4;
  int mb = (wid >> 2) * 64, nb = (wid & 3) * 64;

  #pragma unroll
  for (int i = 0; i < 4; i++)
    #pragma unroll
    for (int j = 0; j < 4; j++) {
      int c = n0 + nb + j * 16 + lr;
      float bv = bias[c];
      #pragma unroll
      for (int r = 0; r < 4; r++) {
        int m = m0 + mb + i * 16 + lg * 4 + r;
        out[(size_t)m * DIM + c] = acc[i][j][r] + bv;
      }
    }
}

// ---------------- launch ----------------
extern "C" void kernel_launch(void* const* d_in, const int* in_sizes, int n_in,
                              void* d_out, int out_size, void* d_ws, size_t ws_size,
                              hipStream_t stream) {
  (void)in_sizes; (void)n_in; (void)out_size; (void)ws_size;
  const float* seq    = (const float*)d_in[0];
  const float* norm_w = (const float*)d_in[1];
  const float* w_qkv  = (const float*)d_in[2];
  const float* pm_k   = (const float*)d_in[3];
  const float* pm_v   = (const float*)d_in[4];
  const float* w_out  = (const float*)d_in[5];
  const float* b_out  = (const float*)d_in[6];
  float* out = (float*)d_out;

  char* ws = (char*)d_ws;
  unsigned short* xn    = (unsigned short*)(ws);              // 33,554,432 B
  unsigned short* wqkvT = (unsigned short*)(ws + 33554432);   //  6,291,456
  unsigned short* woutT = (unsigned short*)(ws + 39845888);   //  2,097,152
  float* costab         = (float*)(ws + 41943040);            //  1,048,576
  float* sintab         = (float*)(ws + 42991616);            //  1,048,576
  unsigned short* q_ws  = (unsigned short*)(ws + 44040192);   // 33,554,432
  unsigned short* k_ws  = (unsigned short*)(ws + 77594624);   // 37,748,736
  unsigned short* v_ws  = (unsigned short*)(ws + 115343360);  // 37,748,736
  unsigned short* attno = (unsigned short*)(ws + 153092096);  // 33,554,432 (end 186,646,528)

  int nb_prep = NB_RMS + NB_TWQKV + NB_TWOUT + NB_ROPE + NB_PM + NB_VPAD;  // 29696
  fused_prep<<<nb_prep, 256, 0, stream>>>(seq, norm_w, w_qkv, w_out, pm_k, pm_v,
                                          xn, wqkvT, woutT, costab, sintab, k_ws, v_ws);
  gemm_qkv<<<dim3(128, 12), 512, 0, stream>>>(xn, wqkvT, costab, sintab, q_ws, k_ws, v_ws);
  attn_k<<<2048, 256, 0, stream>>>(q_ws, k_ws, v_ws, attno);
  gemm_out<<<dim3(128, 4), 512, 0, stream>>>(attno, woutT, b_out, out);
}